// Round 1
// baseline (447.328 us; speedup 1.0000x reference)
//
#include <hip/hip_runtime.h>
#include <stdint.h>

#define D 64
#define NT 8
#define BLOCK 256
#define TPB 16   // 64-edge tiles per block (4 per wave) -> 1024 edges/block

typedef __attribute__((ext_vector_type(8))) short short8;   // 8 bf16
typedef __attribute__((ext_vector_type(4))) float f32x4;

// packed f32x2 -> bf16x2 (RNE), dst.lo = bf16(lo), dst.hi = bf16(hi)
__device__ __forceinline__ unsigned pkbf(float lo, float hi) {
    unsigned r;
    asm("v_cvt_pk_bf16_f32 %0, %1, %2" : "=v"(r) : "v"(lo), "v"(hi));
    return r;
}

__global__ void __launch_bounds__(BLOCK, 2)
edge_mlp_kernel(const float* __restrict__ ef, const int* __restrict__ types,
                const float* __restrict__ W, const float* __restrict__ Bv,
                float* __restrict__ out, int E)
{
    // W^T, bf16, packed in pairs along k: WT[t][col][k/2], XOR-swizzled. 64 KiB.
    __shared__ unsigned WT[NT * 2048];
    __shared__ float BIAS[NT * D];   // 2 KiB

    const int tid = threadIdx.x;

    // ---- Stage: W -> bf16 W^T in LDS (transpose via pair-pack), bias ----
    {
        const int t  = tid >> 5;          // 8 types across 256 threads
        const int k0 = (tid & 31) * 2;    // this thread packs rows k0, k0+1
        const float* w0 = W + (size_t)t * (D * D) + (size_t)k0 * D;
#pragma unroll
        for (int c4 = 0; c4 < D; c4 += 4) {
            f32x4 ra = *(const f32x4*)(w0 + c4);        // row k0,  cols c4..c4+3
            f32x4 rb = *(const f32x4*)(w0 + D + c4);    // row k0+1
#pragma unroll
            for (int j = 0; j < 4; ++j) {
                const int c = c4 + j;
                unsigned idx = (unsigned)(t * 2048 + c * 32 + (k0 >> 1));
                idx ^= (unsigned)((c & 7) << 2);        // bank swizzle (b128-safe)
                WT[idx] = pkbf(ra[j], rb[j]);
            }
        }
        BIAS[tid]       = Bv[tid];
        BIAS[tid + 256] = Bv[tid + 256];
    }
    __syncthreads();   // only barrier; waves independent afterwards

    const int wave = tid >> 6;
    const int lane = tid & 63;
    const int n = lane & 15;   // MFMA col within 16-block / A row m
    const int g = lane >> 4;   // quad index
    const int ntiles = (E + 63) >> 6;

    for (int it = 0; it < 4; ++it) {
        const int ti = blockIdx.x * TPB + wave * 4 + it;
        if (ti >= ntiles) break;
        const int tb = ti << 6;   // first edge of this 64-edge tile

        // type of this lane's edge (lane <-> edge within tile)
        int eidx = tb + lane; if (eidx >= E) eidx = E - 1;
        const int t_lane = types[eidx];

        // ---- A loads: 4 sub-tiles of 16 consecutive rows, fully streaming ----
        f32x4 a[4][4];
#pragma unroll
        for (int mt = 0; mt < 4; ++mt) {
            int row = tb + mt * 16 + n; if (row >= E) row = E - 1;
            const float* rp = ef + (size_t)row * D + g * 8;
            a[mt][0] = *(const f32x4*)(rp);
            a[mt][1] = *(const f32x4*)(rp + 4);
            a[mt][2] = *(const f32x4*)(rp + 32);
            a[mt][3] = *(const f32x4*)(rp + 36);
        }

        // ---- convert to bf16 fragments (packed RNE) ----
        short8 fa[4][2];
#pragma unroll
        for (int mt = 0; mt < 4; ++mt) {
            union { unsigned u[4]; short8 s; } u0, u1;
            u0.u[0] = pkbf(a[mt][0][0], a[mt][0][1]);
            u0.u[1] = pkbf(a[mt][0][2], a[mt][0][3]);
            u0.u[2] = pkbf(a[mt][1][0], a[mt][1][1]);
            u0.u[3] = pkbf(a[mt][1][2], a[mt][1][3]);
            u1.u[0] = pkbf(a[mt][2][0], a[mt][2][1]);
            u1.u[1] = pkbf(a[mt][2][2], a[mt][2][3]);
            u1.u[2] = pkbf(a[mt][3][0], a[mt][3][1]);
            u1.u[3] = pkbf(a[mt][3][2], a[mt][3][3]);
            fa[mt][0] = u0.s;
            fa[mt][1] = u1.s;
        }

        // type of each A-row this lane owns (row m = n in sub-tile mt)
        int tt[4];
#pragma unroll
        for (int mt = 0; mt < 4; ++mt) tt[mt] = __shfl(t_lane, mt * 16 + n);

        f32x4 acc[4][4];
#pragma unroll
        for (int mt = 0; mt < 4; ++mt)
#pragma unroll
            for (int nb = 0; nb < 4; ++nb) acc[mt][nb] = (f32x4){0.f, 0.f, 0.f, 0.f};

        // ---- masked-A accumulation over all 8 types ----
        for (int t = 0; t < NT; ++t) {
            short8 bf[2][4];
#pragma unroll
            for (int kb = 0; kb < 2; ++kb)
#pragma unroll
                for (int nb = 0; nb < 4; ++nb) {
                    const int col = nb * 16 + n;
                    unsigned idx = (unsigned)(t * 2048 + col * 32 + kb * 16 + g * 4);
                    idx ^= (unsigned)((col & 7) << 2);
                    bf[kb][nb] = *(const short8*)&WT[idx];   // ds_read_b128
                }
            const short8 z = (short8)0;
#pragma unroll
            for (int mt = 0; mt < 4; ++mt) {
                const bool m = (tt[mt] == t);
                short8 ma0 = m ? fa[mt][0] : z;   // zero rows of other types
                short8 ma1 = m ? fa[mt][1] : z;
#pragma unroll
                for (int nb = 0; nb < 4; ++nb) {
                    acc[mt][nb] = __builtin_amdgcn_mfma_f32_16x16x32_bf16(ma0, bf[0][nb], acc[mt][nb], 0, 0, 0);
                    acc[mt][nb] = __builtin_amdgcn_mfma_f32_16x16x32_bf16(ma1, bf[1][nb], acc[mt][nb], 0, 0, 0);
                }
            }
        }

        // ---- epilogue: bias (LDS gather by row type) + ReLU, streaming stores ----
#pragma unroll
        for (int mt = 0; mt < 4; ++mt) {
#pragma unroll
            for (int r = 0; r < 4; ++r) {
                const int lrow = mt * 16 + g * 4 + r;   // C/D: col=lane&15, row=g*4+r
                const int row  = tb + lrow;
                const int trow = __shfl(t_lane, lrow);
                if (row < E) {
                    float* orow = out + (size_t)row * D;
#pragma unroll
                    for (int nb = 0; nb < 4; ++nb) {
                        float v = acc[mt][nb][r] + BIAS[trow * D + nb * 16 + n];
                        orow[nb * 16 + n] = v > 0.f ? v : 0.f;
                    }
                }
            }
        }
    }
}

extern "C" void kernel_launch(void* const* d_in, const int* in_sizes, int n_in,
                              void* d_out, int out_size, void* d_ws, size_t ws_size,
                              hipStream_t stream) {
    const float* ef    = (const float*)d_in[0];
    const int*   types = (const int*)d_in[1];
    const float* W     = (const float*)d_in[2];
    const float* Bv    = (const float*)d_in[3];
    float* out = (float*)d_out;
    const int E = in_sizes[1];
    const int ntiles = (E + 63) / 64;
    const int grid = (ntiles + TPB - 1) / TPB;
    hipLaunchKernelGGL(edge_mlp_kernel, dim3(grid), dim3(BLOCK), 0, stream,
                       ef, types, W, Bv, out, E);
}